// Round 5
// baseline (302.585 us; speedup 1.0000x reference)
//
#include <hip/hip_runtime.h>

#define SMOOTH 1e-8f

// Fixed problem shape: [N, C, Z, X, Y] = [4, 2, 160, 160, 160]
constexpr int NROWS = 8000;            // per-(16^3 block, channel) rows
constexpr int WG1   = 3200;            // quarter-slab workgroups

// Kernel 1: per quarter-slab (n,c,zz,xx, 4 z-planes) partial sums, pure
// register accumulation. Thread (xl, s): x-line xl, f4 slot s within the
// 40-f4 y-line; handles slots s, s+16, (s<8: s+32) on 4 planes = 10
// independent float4 load-pairs, no LDS / no barrier in the hot loop.
// Wave-load shape: 16 consecutive lanes = 256B contiguous segment.
__global__ __launch_bounds__(256, 8)
void partial_kernel(const float* __restrict__ pred,
                    const float* __restrict__ gt,
                    float* __restrict__ wsq)
{
    int wg = blockIdx.x;
    const int q4 = wg & 3;  wg >>= 2;
    const int c  = wg & 1;  wg >>= 1;
    const int xx = wg % 10; wg /= 10;
    const int zz = wg % 10;
    const int n  = wg / 10;

    const int t  = threadIdx.x;
    const int s  = t & 15;      // f4 slot within y-line group
    const int xl = t >> 4;      // x-line 0..15
    // f4 index: (((n*2+c)*160 + z)*160 + x)*40 + yf4
    const long base0 =
        ((long)((n * 2 + c) * 160 + zz * 16 + q4 * 4) * 160 + xx * 16) * 40L;

    const float4* p4 = reinterpret_cast<const float4*>(pred);
    const float4* g4 = reinterpret_cast<const float4*>(gt);

    float S0 = 0, G0 = 0, P0 = 0;   // yy = q      (q = s>>2)
    float S1 = 0, G1 = 0, P1 = 0;   // yy = q + 4
    float S2 = 0, G2 = 0, P2 = 0;   // yy = q + 8  (only s < 8)
    const bool j2 = (s < 8);

    #pragma unroll
    for (int plane = 0; plane < 4; ++plane) {
        const long lb = base0 + (long)plane * 6400 + xl * 40 + s;
        const float4 pa = p4[lb];      const float4 ga = g4[lb];
        const float4 pb = p4[lb + 16]; const float4 gb = g4[lb + 16];
        float4 pc, gc;
        if (j2) { pc = p4[lb + 32]; gc = g4[lb + 32]; }

        S0 += (pa.x + pa.y) + (pa.z + pa.w);
        G0 += (ga.x + ga.y) + (ga.z + ga.w);
        P0 += pa.x * ga.x + pa.y * ga.y + pa.z * ga.z + pa.w * ga.w;

        S1 += (pb.x + pb.y) + (pb.z + pb.w);
        G1 += (gb.x + gb.y) + (gb.z + gb.w);
        P1 += pb.x * gb.x + pb.y * gb.y + pb.z * gb.z + pb.w * gb.w;

        if (j2) {
            S2 += (pc.x + pc.y) + (pc.z + pc.w);
            G2 += (gc.x + gc.y) + (gc.z + gc.w);
            P2 += pc.x * gc.x + pc.y * gc.y + pc.z * gc.z + pc.w * gc.w;
        }
    }

    // wave reduce preserving q = s>>2 (lane bits 2,3): xor bits {0,1,4,5}
#define RED4(x) x += __shfl_xor(x, 1, 64); x += __shfl_xor(x, 2, 64); \
                x += __shfl_xor(x, 16, 64); x += __shfl_xor(x, 32, 64);
    RED4(S0) RED4(G0) RED4(P0)
    RED4(S1) RED4(G1) RED4(P1)
    RED4(S2) RED4(G2) RED4(P2)
#undef RED4

    __shared__ float red[4][4][9];   // [wave][q][j*3+comp]
    const int lane = t & 63, wave = t >> 6;
    if ((lane & 51) == 0) {          // lanes 0,4,8,12 -> q = lane>>2
        const int q = lane >> 2;
        float* dst = red[wave][q];
        dst[0] = S0; dst[1] = G0; dst[2] = P0;
        dst[3] = S1; dst[4] = G1; dst[5] = P1;
        dst[6] = S2; dst[7] = G2; dst[8] = P2;
    }
    __syncthreads();

    if (t < 30) {
        const int yy   = t / 3;
        const int comp = t - yy * 3;
        const int q = yy & 3, j = yy >> 2;
        const float val = red[0][q][j * 3 + comp] + red[1][q][j * 3 + comp] +
                          red[2][q][j * 3 + comp] + red[3][q][j * 3 + comp];
        const int row = (((n * 10 + zz) * 10 + xx) * 10 + yy) * 2 + c;
        wsq[(row * 4 + q4) * 3 + comp] = val;   // distinct slot, no atomic
    }
}

// Kernel 2: single WG — combine quarters, nonlinear term, write out[0].
__global__ __launch_bounds__(1024)
void finalize_kernel(const float* __restrict__ wsq,
                     const float* __restrict__ a_p,
                     const float* __restrict__ b_p,
                     float* __restrict__ out)
{
    const int t = threadIdx.x;
    const float a = a_p[0], b = b_p[0];
    float sum = 0.f;

    for (int r = t; r < NROWS; r += 1024) {
        const float4 w0 = *reinterpret_cast<const float4*>(wsq + r * 12);
        const float4 w1 = *reinterpret_cast<const float4*>(wsq + r * 12 + 4);
        const float4 w2 = *reinterpret_cast<const float4*>(wsq + r * 12 + 8);
        const float SP  = w0.x + w0.w + w1.z + w2.y;
        const float SG  = w0.y + w1.x + w1.w + w2.z;
        const float SGP = w0.z + w1.y + w2.x + w2.w;

        const float tp = SGP;
        const float fn = SG - SGP;
        const float fp = SP - SGP;
        const float denom = fp + fn + SMOOTH;
        const float alpha = a + b * ((fp + SMOOTH) / denom);
        const float beta  = a + b * ((fn + SMOOTH) / denom);
        sum += 1.f - (tp + SMOOTH) / (tp + alpha * fp + beta * fn + SMOOTH);
    }

    #pragma unroll
    for (int d = 32; d > 0; d >>= 1) sum += __shfl_down(sum, d, 64);

    __shared__ float wsum[16];
    if ((t & 63) == 0) wsum[t >> 6] = sum;
    __syncthreads();
    if (t == 0) {
        float tot = 0.f;
        #pragma unroll
        for (int i = 0; i < 16; ++i) tot += wsum[i];
        out[0] = tot;
    }
}

extern "C" void kernel_launch(void* const* d_in, const int* in_sizes, int n_in,
                              void* d_out, int out_size, void* d_ws, size_t ws_size,
                              hipStream_t stream)
{
    const float* pred = (const float*)d_in[0];
    const float* gt   = (const float*)d_in[1];
    const float* a_p  = (const float*)d_in[2];
    const float* b_p  = (const float*)d_in[3];
    float* out = (float*)d_out;
    float* wsq = (float*)d_ws;   // 8000 rows * 4 quarters * 3 sums = 384 KB

    partial_kernel<<<WG1, 256, 0, stream>>>(pred, gt, wsq);
    finalize_kernel<<<1, 1024, 0, stream>>>(wsq, a_p, b_p, out);
}

// Round 6
// 282.388 us; speedup vs baseline: 1.0715x; 1.0715x over previous
//
#include <hip/hip_runtime.h>

#define SMOOTH 1e-8f

// Fixed problem shape: [N, C, Z, X, Y] = [4, 2, 160, 160, 160]
constexpr int NROWS = 8000;            // per-(16^3 block, channel) rows
constexpr int WG1   = 3200;            // quarter-slab workgroups

// Kernel 1: per quarter-slab (n,c,zz,xx, 4 z-planes) partial sums, pure
// register accumulation with MAXIMAL memory-level parallelism: all 24
// float4 loads per thread are issued before any accumulation (FIFO
// waitcnt consumption). launch_bounds(256,4) -> 128-VGPR budget so the
// compiler can keep ~20 loads in flight per wave.
__global__ __launch_bounds__(256, 4)
void partial_kernel(const float* __restrict__ pred,
                    const float* __restrict__ gt,
                    float* __restrict__ wsq)
{
    int wg = blockIdx.x;
    const int q4 = wg & 3;  wg >>= 2;
    const int c  = wg & 1;  wg >>= 1;
    const int xx = wg % 10; wg /= 10;
    const int zz = wg % 10;
    const int n  = wg / 10;

    const int t  = threadIdx.x;
    const int s  = t & 15;      // f4 slot within y-line group (16 lanes = 256B)
    const int xl = t >> 4;      // x-line 0..15
    // f4 index: (((n*2+c)*160 + z)*160 + x)*40 + yf4
    const long base0 =
        ((long)((n * 2 + c) * 160 + zz * 16 + q4 * 4) * 160 + xx * 16) * 40L;

    const float4* p4 = reinterpret_cast<const float4*>(pred);
    const float4* g4 = reinterpret_cast<const float4*>(gt);

    const bool j2 = (s < 8);

    long lb0 = base0 + xl * 40 + s;
    long lb1 = lb0 + 6400;
    long lb2 = lb0 + 12800;
    long lb3 = lb0 + 19200;

    // ---- issue phase: 16 unconditional + 8 masked loads, no consumption ----
    float4 pa0 = p4[lb0],      ga0 = g4[lb0];
    float4 pa1 = p4[lb1],      ga1 = g4[lb1];
    float4 pa2 = p4[lb2],      ga2 = g4[lb2];
    float4 pa3 = p4[lb3],      ga3 = g4[lb3];
    float4 pb0 = p4[lb0 + 16], gb0 = g4[lb0 + 16];
    float4 pb1 = p4[lb1 + 16], gb1 = g4[lb1 + 16];
    float4 pb2 = p4[lb2 + 16], gb2 = g4[lb2 + 16];
    float4 pb3 = p4[lb3 + 16], gb3 = g4[lb3 + 16];
    float4 pc0, gc0, pc1, gc1, pc2, gc2, pc3, gc3;
    if (j2) {
        pc0 = p4[lb0 + 32]; gc0 = g4[lb0 + 32];
        pc1 = p4[lb1 + 32]; gc1 = g4[lb1 + 32];
        pc2 = p4[lb2 + 32]; gc2 = g4[lb2 + 32];
        pc3 = p4[lb3 + 32]; gc3 = g4[lb3 + 32];
    }

    // ---- consume phase (FIFO order) ----
    float S0 = 0, G0 = 0, P0 = 0;   // yy = q      (q = s>>2)
    float S1 = 0, G1 = 0, P1 = 0;   // yy = q + 4
    float S2 = 0, G2 = 0, P2 = 0;   // yy = q + 8  (only s < 8)

#define ACC(p, g, S, G, P)                                        \
    S += (p.x + p.y) + (p.z + p.w);                               \
    G += (g.x + g.y) + (g.z + g.w);                               \
    P += p.x * g.x + p.y * g.y + p.z * g.z + p.w * g.w;

    ACC(pa0, ga0, S0, G0, P0)
    ACC(pa1, ga1, S0, G0, P0)
    ACC(pa2, ga2, S0, G0, P0)
    ACC(pa3, ga3, S0, G0, P0)
    ACC(pb0, gb0, S1, G1, P1)
    ACC(pb1, gb1, S1, G1, P1)
    ACC(pb2, gb2, S1, G1, P1)
    ACC(pb3, gb3, S1, G1, P1)
    if (j2) {
        ACC(pc0, gc0, S2, G2, P2)
        ACC(pc1, gc1, S2, G2, P2)
        ACC(pc2, gc2, S2, G2, P2)
        ACC(pc3, gc3, S2, G2, P2)
    }
#undef ACC

    // wave reduce preserving q = s>>2 (lane bits 2,3): xor bits {0,1,4,5}
#define RED4(x) x += __shfl_xor(x, 1, 64); x += __shfl_xor(x, 2, 64); \
                x += __shfl_xor(x, 16, 64); x += __shfl_xor(x, 32, 64);
    RED4(S0) RED4(G0) RED4(P0)
    RED4(S1) RED4(G1) RED4(P1)
    RED4(S2) RED4(G2) RED4(P2)
#undef RED4

    __shared__ float red[4][4][9];   // [wave][q][j*3+comp]
    const int lane = t & 63, wave = t >> 6;
    if ((lane & 51) == 0) {          // lanes 0,4,8,12 -> q = lane>>2
        const int q = lane >> 2;
        float* dst = red[wave][q];
        dst[0] = S0; dst[1] = G0; dst[2] = P0;
        dst[3] = S1; dst[4] = G1; dst[5] = P1;
        dst[6] = S2; dst[7] = G2; dst[8] = P2;
    }
    __syncthreads();

    if (t < 30) {
        const int yy   = t / 3;
        const int comp = t - yy * 3;
        const int q = yy & 3, j = yy >> 2;
        const float val = red[0][q][j * 3 + comp] + red[1][q][j * 3 + comp] +
                          red[2][q][j * 3 + comp] + red[3][q][j * 3 + comp];
        const int row = (((n * 10 + zz) * 10 + xx) * 10 + yy) * 2 + c;
        wsq[(row * 4 + q4) * 3 + comp] = val;   // distinct slot, no atomic
    }
}

// Kernel 2: single WG — combine quarters, nonlinear term, write out[0].
__global__ __launch_bounds__(1024)
void finalize_kernel(const float* __restrict__ wsq,
                     const float* __restrict__ a_p,
                     const float* __restrict__ b_p,
                     float* __restrict__ out)
{
    const int t = threadIdx.x;
    const float a = a_p[0], b = b_p[0];
    float sum = 0.f;

    for (int r = t; r < NROWS; r += 1024) {
        const float4 w0 = *reinterpret_cast<const float4*>(wsq + r * 12);
        const float4 w1 = *reinterpret_cast<const float4*>(wsq + r * 12 + 4);
        const float4 w2 = *reinterpret_cast<const float4*>(wsq + r * 12 + 8);
        const float SP  = w0.x + w0.w + w1.z + w2.y;
        const float SG  = w0.y + w1.x + w1.w + w2.z;
        const float SGP = w0.z + w1.y + w2.x + w2.w;

        const float tp = SGP;
        const float fn = SG - SGP;
        const float fp = SP - SGP;
        const float denom = fp + fn + SMOOTH;
        const float alpha = a + b * ((fp + SMOOTH) / denom);
        const float beta  = a + b * ((fn + SMOOTH) / denom);
        sum += 1.f - (tp + SMOOTH) / (tp + alpha * fp + beta * fn + SMOOTH);
    }

    #pragma unroll
    for (int d = 32; d > 0; d >>= 1) sum += __shfl_down(sum, d, 64);

    __shared__ float wsum[16];
    if ((t & 63) == 0) wsum[t >> 6] = sum;
    __syncthreads();
    if (t == 0) {
        float tot = 0.f;
        #pragma unroll
        for (int i = 0; i < 16; ++i) tot += wsum[i];
        out[0] = tot;
    }
}

extern "C" void kernel_launch(void* const* d_in, const int* in_sizes, int n_in,
                              void* d_out, int out_size, void* d_ws, size_t ws_size,
                              hipStream_t stream)
{
    const float* pred = (const float*)d_in[0];
    const float* gt   = (const float*)d_in[1];
    const float* a_p  = (const float*)d_in[2];
    const float* b_p  = (const float*)d_in[3];
    float* out = (float*)d_out;
    float* wsq = (float*)d_ws;   // 8000 rows * 4 quarters * 3 sums = 384 KB

    partial_kernel<<<WG1, 256, 0, stream>>>(pred, gt, wsq);
    finalize_kernel<<<1, 1024, 0, stream>>>(wsq, a_p, b_p, out);
}

// Round 7
// 252.763 us; speedup vs baseline: 1.1971x; 1.1172x over previous
//
#include <hip/hip_runtime.h>

#define SMOOTH 1e-8f

typedef float f32x4 __attribute__((ext_vector_type(4)));

// Fixed problem shape: [N, C, Z, X, Y] = [4, 2, 160, 160, 160]
constexpr int NROWS = 8000;            // per-(16^3 block, channel) rows
constexpr int WG1   = 3200;            // quarter-slab workgroups

// Kernel 1: quarter-slab (n,c,zz,xx, 4 z-planes). Each WAVE owns one
// z-plane slab row = 16 x-lines * 40 f4 = 640 contiguous f4 (10 KB):
// 10 perfectly unit-stride 1KB wave loads per tensor, all non-temporal
// (L1 bypass), issued in one batch. Binning algebra: load k, lane ->
// f4 slot j = (lane + 24k) mod 40, period 5 in k => 5 static (S,G,P)
// accumulator triplets; yy = 2r + b, b = (lane>>2)&1, r = (j - lane%8)/8.
__global__ __launch_bounds__(256, 4)
void partial_kernel(const float* __restrict__ pred,
                    const float* __restrict__ gt,
                    float* __restrict__ wsq)
{
    int wg = blockIdx.x;
    const int q4 = wg & 3;  wg >>= 2;
    const int c  = wg & 1;  wg >>= 1;
    const int xx = wg % 10; wg /= 10;
    const int zz = wg % 10;
    const int n  = wg / 10;

    const int t    = threadIdx.x;
    const int lane = t & 63;
    const int wave = t >> 6;
    const int z    = zz * 16 + q4 * 4 + wave;   // one z-plane per wave

    // f4 base of this wave's 640-f4 contiguous plane-slab row
    const long pb = ((long)((n * 2 + c) * 160 + z) * 160 + xx * 16) * 40L;

    const f32x4* p4 = reinterpret_cast<const f32x4*>(pred) + pb + lane;
    const f32x4* g4 = reinterpret_cast<const f32x4*>(gt)  + pb + lane;

    // ---- issue phase: 20 unit-stride 1KB nt loads, no consumption ----
    f32x4 P[10], G[10];
    #pragma unroll
    for (int k = 0; k < 10; ++k) {
        P[k] = __builtin_nontemporal_load(p4 + k * 64);
        G[k] = __builtin_nontemporal_load(g4 + k * 64);
    }

    // ---- consume (FIFO): 5 static triplets, m = k mod 5 ----
    float aS[5] = {0, 0, 0, 0, 0};
    float aG[5] = {0, 0, 0, 0, 0};
    float aP[5] = {0, 0, 0, 0, 0};
    #pragma unroll
    for (int k = 0; k < 10; ++k) {
        const int m = k % 5;                    // compile-time
        const f32x4 p = P[k], g = G[k];
        aS[m] += (p.x + p.y) + (p.z + p.w);
        aG[m] += (g.x + g.y) + (g.z + g.w);
        aP[m] += p.x * g.x + p.y * g.y + p.z * g.z + p.w * g.w;
    }

    // ---- rotate m-indexed triplets into r-indexed (yy = 2r + b) ----
    int rr[5];
    #pragma unroll
    for (int m = 0; m < 5; ++m)
        rr[m] = ((lane + 24 * m) % 40) >> 3;    // runtime value, static index

    float bS[5], bG[5], bP[5];
    #pragma unroll
    for (int r = 0; r < 5; ++r) {
        float s = 0.f, g = 0.f, p = 0.f;
        #pragma unroll
        for (int m = 0; m < 5; ++m) {
            const bool hit = (rr[m] == r);      // exactly one m matches
            s += hit ? aS[m] : 0.f;
            g += hit ? aG[m] : 0.f;
            p += hit ? aP[m] : 0.f;
        }
        bS[r] = s; bG[r] = g; bP[r] = p;
    }

    // ---- xor-reduce over lane bits {0,1,3,4,5}: preserves b = bit2 ----
    #pragma unroll
    for (int r = 0; r < 5; ++r) {
        #pragma unroll
        for (int d = 0; d < 5; ++d) {
            const int msk = (d < 2) ? (1 << d) : (1 << (d + 1));  // 1,2,8,16,32
            bS[r] += __shfl_xor(bS[r], msk, 64);
            bG[r] += __shfl_xor(bG[r], msk, 64);
            bP[r] += __shfl_xor(bP[r], msk, 64);
        }
    }

    __shared__ float red[4][2][15];             // [wave][b][r*3+comp]
    const int b = (lane >> 2) & 1;
    if ((lane & 59) == 0) {                     // lanes 0 (b=0) and 4 (b=1)
        #pragma unroll
        for (int r = 0; r < 5; ++r) {
            red[wave][b][r * 3 + 0] = bS[r];
            red[wave][b][r * 3 + 1] = bG[r];
            red[wave][b][r * 3 + 2] = bP[r];
        }
    }
    __syncthreads();

    if (t < 30) {
        const int yy   = t / 3;
        const int comp = t - yy * 3;
        const int bb = yy & 1, r = yy >> 1;
        const float val = red[0][bb][r * 3 + comp] + red[1][bb][r * 3 + comp] +
                          red[2][bb][r * 3 + comp] + red[3][bb][r * 3 + comp];
        const int row = (((n * 10 + zz) * 10 + xx) * 10 + yy) * 2 + c;
        wsq[(row * 4 + q4) * 3 + comp] = val;   // distinct slot, no atomic
    }
}

// Kernel 2: single WG — combine quarters, nonlinear term, write out[0].
__global__ __launch_bounds__(1024)
void finalize_kernel(const float* __restrict__ wsq,
                     const float* __restrict__ a_p,
                     const float* __restrict__ b_p,
                     float* __restrict__ out)
{
    const int t = threadIdx.x;
    const float a = a_p[0], b = b_p[0];
    float sum = 0.f;

    for (int r = t; r < NROWS; r += 1024) {
        const float4 w0 = *reinterpret_cast<const float4*>(wsq + r * 12);
        const float4 w1 = *reinterpret_cast<const float4*>(wsq + r * 12 + 4);
        const float4 w2 = *reinterpret_cast<const float4*>(wsq + r * 12 + 8);
        const float SP  = w0.x + w0.w + w1.z + w2.y;
        const float SG  = w0.y + w1.x + w1.w + w2.z;
        const float SGP = w0.z + w1.y + w2.x + w2.w;

        const float tp = SGP;
        const float fn = SG - SGP;
        const float fp = SP - SGP;
        const float denom = fp + fn + SMOOTH;
        const float alpha = a + b * ((fp + SMOOTH) / denom);
        const float beta  = a + b * ((fn + SMOOTH) / denom);
        sum += 1.f - (tp + SMOOTH) / (tp + alpha * fp + beta * fn + SMOOTH);
    }

    #pragma unroll
    for (int d = 32; d > 0; d >>= 1) sum += __shfl_down(sum, d, 64);

    __shared__ float wsum[16];
    if ((t & 63) == 0) wsum[t >> 6] = sum;
    __syncthreads();
    if (t == 0) {
        float tot = 0.f;
        #pragma unroll
        for (int i = 0; i < 16; ++i) tot += wsum[i];
        out[0] = tot;
    }
}

extern "C" void kernel_launch(void* const* d_in, const int* in_sizes, int n_in,
                              void* d_out, int out_size, void* d_ws, size_t ws_size,
                              hipStream_t stream)
{
    const float* pred = (const float*)d_in[0];
    const float* gt   = (const float*)d_in[1];
    const float* a_p  = (const float*)d_in[2];
    const float* b_p  = (const float*)d_in[3];
    float* out = (float*)d_out;
    float* wsq = (float*)d_ws;   // 8000 rows * 4 quarters * 3 sums = 384 KB

    partial_kernel<<<WG1, 256, 0, stream>>>(pred, gt, wsq);
    finalize_kernel<<<1, 1024, 0, stream>>>(wsq, a_p, b_p, out);
}